// Round 6
// baseline (251.534 us; speedup 1.0000x reference)
//
#include <hip/hip_runtime.h>
#include <hip/hip_bf16.h>
#include <math.h>

#define DEV static __device__ __forceinline__

typedef float f32x4 __attribute__((ext_vector_type(4)));
typedef short s16x8 __attribute__((ext_vector_type(8)));
typedef unsigned short u16;
typedef unsigned int u32;
typedef u16 u16x4 __attribute__((ext_vector_type(4)));
typedef u16 u16x8 __attribute__((ext_vector_type(8)));

#define SSCALE 0.35355339059327379f   // 64^-0.25
// SSCALE * sqrt(log2(e)): folds the exp->exp2 conversion into the symmetric
// qk scaling, so softmax uses raw v_exp_f32 with no per-element multiply.
#define SS2 0.42466089345200966f

DEV f32x4 mfma16(s16x8 a, s16x8 b, f32x4 c) {
  return __builtin_amdgcn_mfma_f32_16x16x32_bf16(a, b, c, 0, 0, 0);
}

DEV float bf2f(u16 x) { u32 u = ((u32)x) << 16; float f; __builtin_memcpy(&f, &u, 4); return f; }
DEV u16 f2bf(float x) { __hip_bfloat16 b = __float2bfloat16(x); u16 r; __builtin_memcpy(&r, &b, 2); return r; }

// packed f32x2 -> bf16x2 in one VALU op (T12 recipe; no builtin on gfx950)
DEV u32 cvtpk(float lo, float hi) {
  u32 r;
  asm("v_cvt_pk_bf16_f32 %0, %1, %2" : "=v"(r) : "v"(lo), "v"(hi));
  return r;
}

DEV float fexp2(float x) {
#if __has_builtin(__builtin_amdgcn_exp2f)
  return __builtin_amdgcn_exp2f(x);
#else
  return exp2f(x);
#endif
}

DEV void gload_lds16(const void* g, void* l) {
  __builtin_amdgcn_global_load_lds((const __attribute__((address_space(1))) u32*)g,
                                   (__attribute__((address_space(3))) u32*)l, 16, 0, 0);
}

// ---------------------------------------------------------------------------
// prep (multi-mode by block range):
//   [0,2048)    x0|x1 -> Xb bf16 (vectorized)
//   [2048,2144) 96 LDS-tiled 64x64 transposes: Wqk^T,Wv^T -> btqkv;
//               W1a^T -> btF[:, :256]; W2^T -> bt2
//   [2144,2656) Wc = Wo @ W1b (f32 accum, 8-way ILP) -> btF[:, 256:]
//   [2656,2658) bc = b1 + bo @ W1b (f32, 8-way ILP)
// ---------------------------------------------------------------------------
__global__ __launch_bounds__(256) void k_prep(
    const float* __restrict__ x0, const float* __restrict__ x1,
    const float* __restrict__ Wqk, const float* __restrict__ Wv,
    const float* __restrict__ Wo, const float* __restrict__ W1,
    const float* __restrict__ W2, const float* __restrict__ bo,
    const float* __restrict__ b1,
    u16* __restrict__ btqkv, u16* __restrict__ btF,
    u16* __restrict__ bt2, float* __restrict__ bc, u16* __restrict__ Xb)
{
  const int blk = blockIdx.x, tid = threadIdx.x;
  if (blk < 2048) {               // x convert: 2048 elems per block
    int idx = blk * 2048 + tid * 8;
    const float* src = (idx < 2097152) ? (x0 + idx) : (x1 + (idx - 2097152));
    f32x4 va = *(const f32x4*)src;
    f32x4 vb = *(const f32x4*)(src + 4);
    u16x8 o;
#pragma unroll
    for (int j = 0; j < 4; ++j) { o[j] = f2bf(va[j]); o[4 + j] = f2bf(vb[j]); }
    *(u16x8*)(Xb + idx) = o;
  } else if (blk < 2144) {        // transpose tiles
    __shared__ float T[64][65];
    int tb = blk - 2048;
    const float* src; u16* dst; int sld, dld, kr0, c0, drow0;
    if (tb < 16)      { src = Wqk; dst = btqkv; sld = 256; dld = 256; drow0 = 0;
                        kr0 = (tb >> 2) * 64; c0 = (tb & 3) * 64; }
    else if (tb < 32) { tb -= 16; src = Wv; dst = btqkv; sld = 256; dld = 256; drow0 = 256;
                        kr0 = (tb >> 2) * 64; c0 = (tb & 3) * 64; }
    else if (tb < 64) { tb -= 32; src = W1; dst = btF; sld = 512; dld = 512; drow0 = 0;
                        kr0 = (tb >> 3) * 64; c0 = (tb & 7) * 64; }
    else              { tb -= 64; src = W2; dst = bt2; sld = 256; dld = 512; drow0 = 0;
                        kr0 = (tb >> 2) * 64; c0 = (tb & 3) * 64; }
    int r = tid >> 2, cq = (tid & 3) * 16;
#pragma unroll
    for (int q = 0; q < 4; ++q) {
      f32x4 v = *(const f32x4*)(src + (size_t)(kr0 + r) * sld + c0 + cq + q * 4);
#pragma unroll
      for (int e = 0; e < 4; ++e) T[r][cq + q * 4 + e] = v[e];
    }
    __syncthreads();
    int c = tid >> 2, kq = (tid & 3) * 16;
#pragma unroll
    for (int q = 0; q < 2; ++q) {
      u16x8 o;
#pragma unroll
      for (int e = 0; e < 8; ++e) o[e] = f2bf(T[kq + q * 8 + e][c]);
      *(u16x8*)(dst + (size_t)(drow0 + c0 + c) * dld + kr0 + kq + q * 8) = o;
    }
  } else if (blk < 2656) {        // Wc^T[n][i] = sum_j W1[(256+j)][n] * Wo[i][j]
    int wb = blk - 2144;
    int i = wb >> 1;
    int n = (wb & 1) * 256 + tid;
    float a[8] = {0.f, 0.f, 0.f, 0.f, 0.f, 0.f, 0.f, 0.f};
    for (int j = 0; j < 256; j += 8) {
#pragma unroll
      for (int e = 0; e < 8; ++e)
        a[e] = fmaf(Wo[i * 256 + j + e], W1[(size_t)(256 + j + e) * 512 + n], a[e]);
    }
    btF[(size_t)n * 512 + 256 + i] =
        f2bf(((a[0] + a[1]) + (a[2] + a[3])) + ((a[4] + a[5]) + (a[6] + a[7])));
  } else {                        // bc[n] = b1[n] + sum_j bo[j]*W1[(256+j)][n]
    int n = (blk - 2656) * 256 + tid;
    float p[8] = {0.f, 0.f, 0.f, 0.f, 0.f, 0.f, 0.f, 0.f};
    for (int j = 0; j < 256; j += 8) {
#pragma unroll
      for (int e = 0; e < 8; ++e)
        p[e] = fmaf(bo[j + e], W1[(size_t)(256 + j + e) * 512 + n], p[e]);
    }
    bc[n] = b1[n] + (((p[0] + p[1]) + (p[2] + p[3])) + ((p[4] + p[5]) + (p[6] + p[7])));
  }
}

// ---------------------------------------------------------------------------
// GEMM: C[16384 x Ncols] = A(bf16,[M][KD], split A1|A2 at K1) @ Bt^T
// Bt is [Ncols][KD] bf16. 128xBN tile, 4 waves, BK=32, double-buffered
// global_load_lds, XOR-swizzled LDS.
// EPI 0: qk/vt scatter (+bias,*SS2 / +bias, packed-n stores)
// EPI 1: bf16 out (+bias)      EPI 3: f32 out (+bias +residual x)
// ---------------------------------------------------------------------------
template <int KD, int K1, int EPI, int BN>
__global__ __launch_bounds__(256, 2) void k_gemm(
    const u16* __restrict__ A1, const u16* __restrict__ A2,
    const u16* __restrict__ Bt,
    const float* __restrict__ bias, const float* __restrict__ bias2,
    const float* __restrict__ res0, const float* __restrict__ res1,
    u16* __restrict__ outb, u16* __restrict__ outb2,
    float* __restrict__ outf, int Ncols)
{
  constexpr int MR = (BN == 128) ? 4 : 2;       // row-tiles per wave
  __shared__ char lds[16384 + 2 * BN * 64];
  char* ldsA = lds;
  char* ldsB = lds + 16384;
  const int tid = threadIdx.x;
  const int lane = tid & 63;
  const int w = tid >> 6;
  const int wm = (BN == 128) ? (w >> 1) : w;
  const int wn = (BN == 128) ? (w & 1) : 0;
  const int g = lane >> 4, li = lane & 15;
  const int m0 = blockIdx.x * 128, n0 = blockIdx.y * BN;

  auto stage = [&](int buf, int t) {
    const int k0 = t * 32;
#pragma unroll
    for (int it = 0; it < 2; ++it) {
      int chunk = it * 256 + w * 64 + lane;
      int row = chunk >> 2, c = chunk & 3;
      int kc = k0 + ((c ^ ((row >> 1) & 3)) << 3);
      const u16* src = (kc < K1) ? (A1 + (size_t)(m0 + row) * K1 + kc)
                                 : (A2 + (size_t)(m0 + row) * (KD - K1) + (kc - K1));
      gload_lds16(src, ldsA + buf * 8192 + (it * 256 + w * 64) * 16);
    }
#pragma unroll
    for (int it = 0; it < BN / 64; ++it) {
      int chunk = it * 256 + w * 64 + lane;
      int row = chunk >> 2, c = chunk & 3;
      int kc = k0 + ((c ^ ((row >> 1) & 3)) << 3);
      gload_lds16(Bt + (size_t)(n0 + row) * KD + kc,
                  ldsB + buf * (BN * 64) + (it * 256 + w * 64) * 16);
    }
  };

  f32x4 acc[MR][4] = {};

  stage(0, 0);
  __syncthreads();
  const int NT = KD / 32;
  for (int t = 0; t < NT; ++t) {
    if (t + 1 < NT) stage((t + 1) & 1, t + 1);
    const char* bufA = ldsA + (t & 1) * 8192;
    const char* bufB = ldsB + (t & 1) * (BN * 64);
    s16x8 af[MR], bfr[4];
#pragma unroll
    for (int rt = 0; rt < MR; ++rt) {
      int row = wm * (MR * 16) + rt * 16 + li;
      af[rt] = *(const s16x8*)(bufA + row * 64 + ((g ^ ((row >> 1) & 3)) << 4));
    }
#pragma unroll
    for (int ct = 0; ct < 4; ++ct) {
      int col = wn * 64 + ct * 16 + li;
      bfr[ct] = *(const s16x8*)(bufB + col * 64 + ((g ^ ((col >> 1) & 3)) << 4));
    }
#pragma unroll
    for (int rt = 0; rt < MR; ++rt)
#pragma unroll
      for (int ct = 0; ct < 4; ++ct)
        acc[rt][ct] = mfma16(af[rt], bfr[ct], acc[rt][ct]);
    __syncthreads();
  }

#pragma unroll
  for (int rt = 0; rt < MR; ++rt) {
#pragma unroll
    for (int ct = 0; ct < 4; ++ct) {
      const int growb = m0 + wm * (MR * 16) + rt * 16 + g * 4;   // base row (r=0)
      const int gcol = n0 + wn * 64 + ct * 16 + li;
      if (EPI == 0) {
        const int dir = growb >> 13, bb = (growb >> 11) & 3, n = growb & 2047;
        if (gcol < 256) {
          const int h = gcol >> 6, dh = gcol & 63;
#pragma unroll
          for (int r = 0; r < 4; ++r) {
            float q = (acc[rt][ct][r] + bias[gcol]) * SS2;
            outb[((size_t)(dir * 16 + bb * 4 + h) * 2048 + (n + r)) * 64 + dh] = f2bf(q);
          }
        } else {
          const int c2 = gcol - 256, h = c2 >> 6, dh = c2 & 63;
          u16x4 pk;
#pragma unroll
          for (int r = 0; r < 4; ++r) pk[r] = f2bf(acc[rt][ct][r] + bias2[c2]);
          *(u16x4*)(outb2 + ((size_t)(dir * 16 + bb * 4 + h) * 64 + dh) * 2048 + n) = pk;
        }
      } else if (EPI == 1) {
#pragma unroll
        for (int r = 0; r < 4; ++r)
          outb[(size_t)(growb + r) * Ncols + gcol] = f2bf(acc[rt][ct][r] + bias[gcol]);
      } else {
#pragma unroll
        for (int r = 0; r < 4; ++r) {
          int grow = growb + r;
          float x = (grow < 8192) ? res0[(size_t)grow * 256 + gcol]
                                  : res1[(size_t)(grow - 8192) * 256 + gcol];
          outf[(size_t)grow * 256 + gcol] = acc[rt][ct][r] + bias[gcol] + x;
        }
      }
    }
  }
}

// ---------------------------------------------------------------------------
// attention v5: in-block split-KV (8 waves: half 0/1 x 4 q-waves of 32 rows).
// K staged via gload_lds (shared by 4 waves); V read DIRECTLY from L2
// (per-XCD working set ~2MB, L2-resident -> LDS staging was pure overhead).
// P stays in registers: permlane32_swap redistribution (T12) + cvt_pk asm.
// Row sums via ones-MFMA (B-operand = all 1.0bf16): accs[qt][r] = full
// rowsum at exactly the lane that needs it -> no cross-lane reduce.
// Logits pre-scaled by sqrt(log2 e) -> softmax is raw v_exp_f32.
// ---------------------------------------------------------------------------
__global__ __launch_bounds__(512, 4) void k_attn(
    const u16* __restrict__ qk, const u16* __restrict__ vt, u16* __restrict__ m_all)
{
  __shared__ char Kl[2][2][8192];   // [half][buf]
  __shared__ float lsmall[128];     // half0 row-sums for combine
  const int tid = threadIdx.x, lane = tid & 63, w = tid >> 6;
  const int half = w >> 2, wq = w & 3;
  const int g = lane >> 4, li = lane & 15;
  const int sw = (blockIdx.x & 7) * 64 + (blockIdx.x >> 3);  // XCD chunking (512=8*64)
  const int qblk = sw & 15;
  const int p = sw >> 4;
  const int dir = p >> 4, bh = p & 15;
  const char* Qg = (const char*)qk + (size_t)p * 262144;
  const char* Kg = (const char*)qk + (size_t)((dir ^ 1) * 16 + bh) * 262144;
  const u16*  Vg = vt + (size_t)((dir ^ 1) * 16 + bh) * 131072;  // [dh=64][n=2048]
  const int q0 = qblk * 128 + wq * 32;
  const int perm = (li & 3) | ((li & 4) << 1) | ((li & 8) >> 1);  // swap bits 2,3

  // Q fragments in registers (reused across the whole j loop)
  s16x8 qf[2][2];
#pragma unroll
  for (int qt = 0; qt < 2; ++qt)
#pragma unroll
    for (int h = 0; h < 2; ++h)
      qf[qt][h] = *(const s16x8*)(Qg + (size_t)(q0 + qt * 16 + li) * 128 + h * 64 + g * 16);

  // all-ones B-fragment: V[k][*]=1 -> mfma gives row sums of P
  s16x8 onesf;
#pragma unroll
  for (int e = 0; e < 8; ++e) onesf[e] = (short)0x3F80;

  auto stageK = [&](int buf, int jt) {
    const int kb = half * 1024 + jt * 64;
#pragma unroll
    for (int it = 0; it < 2; ++it) {
      int chunk = it * 256 + wq * 64 + lane;
      int row = chunk >> 3, c = chunk & 7;
      int cc = (c ^ (row & 7)) << 4;
      gload_lds16(Kg + (size_t)(kb + row) * 128 + cc, &Kl[half][buf][chunk * 16]);
    }
  };

  f32x4 acco[2][4] = {};
  f32x4 accs[2] = {};

  stageK(0, 0);
  __syncthreads();
  for (int jt = 0; jt < 16; ++jt) {
    if (jt + 1 < 16) stageK((jt + 1) & 1, jt + 1);
    const char* Kb = &Kl[half][jt & 1][0];
    const int keyb = half * 1024 + jt * 64;   // key element base in V rows

    // S^T tiles: mfma(K,Q). K rows loaded at perm(li) so lane (g,li) holds
    // keys kt*16 + 8*(g&1) + 4*(g>>1) + r for q-row qt*16+li.
    u32 pw[4][2][2];  // [kt][qt][word]: packed bf16 pairs of exp2(S')
#pragma unroll
    for (int kt = 0; kt < 4; ++kt) {
      const int krow = kt * 16 + perm;
      s16x8 kf0 = *(const s16x8*)(Kb + krow * 128 + ((g ^ (krow & 7)) << 4));
      s16x8 kf1 = *(const s16x8*)(Kb + krow * 128 + (((4 + g) ^ (krow & 7)) << 4));
#pragma unroll
      for (int qt = 0; qt < 2; ++qt) {
        f32x4 s = {0.f, 0.f, 0.f, 0.f};
        s = mfma16(kf0, qf[qt][0], s);
        s = mfma16(kf1, qf[qt][1], s);
        pw[kt][qt][0] = cvtpk(fexp2(s[0]), fexp2(s[1]));
        pw[kt][qt][1] = cvtpk(fexp2(s[2]), fexp2(s[3]));
      }
    }

    // Build PV A-frags in-register: two permlane32_swap per (ks,qt).
    s16x8 pf[2][2];  // [ks][qt]
#pragma unroll
    for (int ks = 0; ks < 2; ++ks)
#pragma unroll
      for (int qt = 0; qt < 2; ++qt) {
        u32 a0 = pw[ks * 2][qt][0], b0 = pw[ks * 2 + 1][qt][0];
        u32 a1 = pw[ks * 2][qt][1], b1 = pw[ks * 2 + 1][qt][1];
        asm("v_permlane32_swap_b32 %0, %1" : "+v"(a0), "+v"(b0));
        asm("v_permlane32_swap_b32 %0, %1" : "+v"(a1), "+v"(b1));
        u32 words[4] = {a0, a1, b0, b1};
        __builtin_memcpy(&pf[ks][qt], words, 16);
      }

    // O += P V  (V fragments straight from L2); rowsums += P * ones
#pragma unroll
    for (int ks = 0; ks < 2; ++ks) {
      accs[0] = mfma16(pf[ks][0], onesf, accs[0]);
      accs[1] = mfma16(pf[ks][1], onesf, accs[1]);
#pragma unroll
      for (int dt = 0; dt < 4; ++dt) {
        s16x8 vfr = *(const s16x8*)(Vg + (size_t)(dt * 16 + li) * 2048 +
                                    keyb + ks * 32 + g * 8);
        acco[0][dt] = mfma16(pf[ks][0], vfr, acco[0][dt]);
        acco[1][dt] = mfma16(pf[ks][1], vfr, acco[1][dt]);
      }
    }
    __syncthreads();
  }

  // in-block half-combine through freed K-LDS (32KB O scratch) + lsmall.
  // accs[qt][r] at lane (g,li) = rowsum for q-row qt*16+g*4+r (all li equal).
  float* scr = (float*)&Kl[0][0][0];
  if (half == 0) {
#pragma unroll
    for (int qt = 0; qt < 2; ++qt)
#pragma unroll
      for (int dt = 0; dt < 4; ++dt)
        *(f32x4*)(scr + wq * 2048 + lane * 32 + (((qt * 4 + dt) * 4) ^ ((lane & 7) << 2))) =
            acco[qt][dt];
    if (li == 0) {
#pragma unroll
      for (int qt = 0; qt < 2; ++qt)
#pragma unroll
        for (int r = 0; r < 4; ++r)
          lsmall[wq * 32 + qt * 16 + g * 4 + r] = accs[qt][r];
    }
  }
  __syncthreads();
  if (half == 1) {
    const int bb = bh >> 2, h = bh & 3;
#pragma unroll
    for (int qt = 0; qt < 2; ++qt) {
      f32x4 lo = *(const f32x4*)(lsmall + wq * 32 + qt * 16 + g * 4);
      f32x4 inv;
#pragma unroll
      for (int r = 0; r < 4; ++r) inv[r] = 1.0f / (accs[qt][r] + lo[r]);
      const size_t rowb = (size_t)dir * 8192 + (size_t)bb * 2048 + q0 + qt * 16 + g * 4;
#pragma unroll
      for (int dt = 0; dt < 4; ++dt) {
        f32x4 o = *(const f32x4*)(scr + wq * 2048 + lane * 32 +
                                  (((qt * 4 + dt) * 4) ^ ((lane & 7) << 2)));
#pragma unroll
        for (int r = 0; r < 4; ++r)
          m_all[(rowb + r) * 256 + h * 64 + dt * 16 + li] =
              f2bf((acco[qt][dt][r] + o[r]) * inv[r]);
      }
    }
  }
}

// ---------------------------------------------------------------------------
// layernorm (over 512) + exact gelu; one wave per row
// ---------------------------------------------------------------------------
__global__ __launch_bounds__(256) void k_ln_gelu(
    const u16* __restrict__ h, const float* __restrict__ lg,
    const float* __restrict__ lb, u16* __restrict__ o)
{
  int lane = threadIdx.x & 63;
  size_t row = blockIdx.x * 4 + (threadIdx.x >> 6);
  s16x8 v = *(const s16x8*)(h + row * 512 + lane * 8);
  float f[8], s = 0.f, s2 = 0.f;
#pragma unroll
  for (int j = 0; j < 8; ++j) { f[j] = bf2f((u16)v[j]); s += f[j]; s2 += f[j] * f[j]; }
#pragma unroll
  for (int m = 1; m < 64; m <<= 1) { s += __shfl_xor(s, m); s2 += __shfl_xor(s2, m); }
  float mu = s * (1.0f / 512.0f);
  float var = s2 * (1.0f / 512.0f) - mu * mu;
  float rs = rsqrtf(var + 1e-5f);
  s16x8 ov;
#pragma unroll
  for (int j = 0; j < 8; ++j) {
    int c = lane * 8 + j;
    float y = (f[j] - mu) * rs * lg[c] + lb[c];
    float ge = 0.5f * y * (1.0f + erff(y * 0.70710678118654752f));
    ov[j] = (short)f2bf(ge);
  }
  *(s16x8*)(o + row * 512 + lane * 8) = ov;
}

// ---------------------------------------------------------------------------
extern "C" void kernel_launch(void* const* d_in, const int* in_sizes, int n_in,
                              void* d_out, int out_size, void* d_ws, size_t ws_size,
                              hipStream_t stream)
{
  const float* x0  = (const float*)d_in[0];
  const float* x1  = (const float*)d_in[1];
  const float* Wqk = (const float*)d_in[2];
  const float* bqk = (const float*)d_in[3];
  const float* Wv  = (const float*)d_in[4];
  const float* bv  = (const float*)d_in[5];
  const float* Wo  = (const float*)d_in[6];
  const float* bo  = (const float*)d_in[7];
  const float* W1  = (const float*)d_in[8];
  const float* b1  = (const float*)d_in[9];
  const float* lg  = (const float*)d_in[10];
  const float* lb  = (const float*)d_in[11];
  const float* W2  = (const float*)d_in[12];
  const float* b2  = (const float*)d_in[13];
  float* out = (float*)d_out;
  char* ws = (char*)d_ws;

  u16*   Xb    = (u16*)(ws + 0);          // 16384x256 bf16
  u16*   qk    = (u16*)(ws + 8388608);    // [2][4][4][2048][64] bf16 (scaled)
  u16*   vt    = (u16*)(ws + 16777216);   // [2][4][4][64][2048] bf16 (V^T)
  u16*   m_all = (u16*)(ws + 25165824);   // 16384x256 bf16 (normalized attn out)
  u16*   hpre  = (u16*)(ws + 33554432);   // 16384x512 bf16
  u16*   gact  = (u16*)(ws + 50331648);   // 16384x512 bf16
  u16*   btqkv = (u16*)(ws + 67108864);   // [512][256]
  u16*   btF   = (u16*)(ws + 67371008);   // [512][512]: [:, :256]=W1a^T, [:, 256:]=Wc^T
  u16*   bt2   = (u16*)(ws + 67895296);   // [256][512]
  float* bc    = (float*)(ws + 68419584); // [512] fused FFN1 bias

  k_prep<<<dim3(2658), dim3(256), 0, stream>>>(x0, x1, Wqk, Wv, Wo, W1, W2, bo, b1,
                                               btqkv, btF, bt2, bc, Xb);
  k_gemm<256, 256, 0, 128><<<dim3(128, 4), dim3(256), 0, stream>>>(
      Xb, nullptr, btqkv, bqk, bv, nullptr, nullptr, qk, vt, nullptr, 512);
  k_attn<<<dim3(512), dim3(512), 0, stream>>>(qk, vt, m_all);
  k_gemm<512, 256, 1, 128><<<dim3(128, 4), dim3(256), 0, stream>>>(
      Xb, m_all, btF, bc, nullptr, nullptr, nullptr, hpre, nullptr, nullptr, 512);
  k_ln_gelu<<<dim3(4096), dim3(256), 0, stream>>>(hpre, lg, lb, gact);
  k_gemm<512, 512, 3, 64><<<dim3(128, 4), dim3(256), 0, stream>>>(
      gact, nullptr, bt2, b2, nullptr, x0, x1, nullptr, nullptr, out, 256);
}

// Round 7
// 245.254 us; speedup vs baseline: 1.0256x; 1.0256x over previous
//
#include <hip/hip_runtime.h>
#include <hip/hip_bf16.h>
#include <math.h>

#define DEV static __device__ __forceinline__

typedef float f32x4 __attribute__((ext_vector_type(4)));
typedef short s16x8 __attribute__((ext_vector_type(8)));
typedef unsigned short u16;
typedef unsigned int u32;
typedef u16 u16x4 __attribute__((ext_vector_type(4)));
typedef u16 u16x8 __attribute__((ext_vector_type(8)));

#define SSCALE 0.35355339059327379f   // 64^-0.25
// SSCALE * sqrt(log2(e)): folds the exp->exp2 conversion into the symmetric
// qk scaling, so softmax uses raw v_exp_f32 with no per-element multiply.
#define SS2 0.42466089345200966f

DEV f32x4 mfma16(s16x8 a, s16x8 b, f32x4 c) {
  return __builtin_amdgcn_mfma_f32_16x16x32_bf16(a, b, c, 0, 0, 0);
}

DEV float bf2f(u16 x) { u32 u = ((u32)x) << 16; float f; __builtin_memcpy(&f, &u, 4); return f; }
DEV u16 f2bf(float x) { __hip_bfloat16 b = __float2bfloat16(x); u16 r; __builtin_memcpy(&r, &b, 2); return r; }

// packed f32x2 -> bf16x2 in one VALU op (T12 recipe; no builtin on gfx950)
DEV u32 cvtpk(float lo, float hi) {
  u32 r;
  asm("v_cvt_pk_bf16_f32 %0, %1, %2" : "=v"(r) : "v"(lo), "v"(hi));
  return r;
}

DEV float fexp2(float x) {
#if __has_builtin(__builtin_amdgcn_exp2f)
  return __builtin_amdgcn_exp2f(x);
#else
  return exp2f(x);
#endif
}

DEV void gload_lds16(const void* g, void* l) {
  __builtin_amdgcn_global_load_lds((const __attribute__((address_space(1))) u32*)g,
                                   (__attribute__((address_space(3))) u32*)l, 16, 0, 0);
}

// ---------------------------------------------------------------------------
// prep (multi-mode by block range):
//   [0,2048)    x0|x1 -> Xb bf16 (vectorized)
//   [2048,2144) 96 LDS-tiled 64x64 transposes: Wqk^T,Wv^T -> btqkv;
//               W1a^T -> btF[:, :256]; W2^T -> bt2
//   [2144,2656) Wc = Wo @ W1b (f32 accum, 8-way ILP) -> btF[:, 256:]
//   [2656,2658) bc = b1 + bo @ W1b (f32, 8-way ILP)
// ---------------------------------------------------------------------------
__global__ __launch_bounds__(256) void k_prep(
    const float* __restrict__ x0, const float* __restrict__ x1,
    const float* __restrict__ Wqk, const float* __restrict__ Wv,
    const float* __restrict__ Wo, const float* __restrict__ W1,
    const float* __restrict__ W2, const float* __restrict__ bo,
    const float* __restrict__ b1,
    u16* __restrict__ btqkv, u16* __restrict__ btF,
    u16* __restrict__ bt2, float* __restrict__ bc, u16* __restrict__ Xb)
{
  const int blk = blockIdx.x, tid = threadIdx.x;
  if (blk < 2048) {               // x convert: 2048 elems per block
    int idx = blk * 2048 + tid * 8;
    const float* src = (idx < 2097152) ? (x0 + idx) : (x1 + (idx - 2097152));
    f32x4 va = *(const f32x4*)src;
    f32x4 vb = *(const f32x4*)(src + 4);
    u16x8 o;
#pragma unroll
    for (int j = 0; j < 4; ++j) { o[j] = f2bf(va[j]); o[4 + j] = f2bf(vb[j]); }
    *(u16x8*)(Xb + idx) = o;
  } else if (blk < 2144) {        // transpose tiles
    __shared__ float T[64][65];
    int tb = blk - 2048;
    const float* src; u16* dst; int sld, dld, kr0, c0, drow0;
    if (tb < 16)      { src = Wqk; dst = btqkv; sld = 256; dld = 256; drow0 = 0;
                        kr0 = (tb >> 2) * 64; c0 = (tb & 3) * 64; }
    else if (tb < 32) { tb -= 16; src = Wv; dst = btqkv; sld = 256; dld = 256; drow0 = 256;
                        kr0 = (tb >> 2) * 64; c0 = (tb & 3) * 64; }
    else if (tb < 64) { tb -= 32; src = W1; dst = btF; sld = 512; dld = 512; drow0 = 0;
                        kr0 = (tb >> 3) * 64; c0 = (tb & 7) * 64; }
    else              { tb -= 64; src = W2; dst = bt2; sld = 256; dld = 512; drow0 = 0;
                        kr0 = (tb >> 2) * 64; c0 = (tb & 3) * 64; }
    int r = tid >> 2, cq = (tid & 3) * 16;
#pragma unroll
    for (int q = 0; q < 4; ++q) {
      f32x4 v = *(const f32x4*)(src + (size_t)(kr0 + r) * sld + c0 + cq + q * 4);
#pragma unroll
      for (int e = 0; e < 4; ++e) T[r][cq + q * 4 + e] = v[e];
    }
    __syncthreads();
    int c = tid >> 2, kq = (tid & 3) * 16;
#pragma unroll
    for (int q = 0; q < 2; ++q) {
      u16x8 o;
#pragma unroll
      for (int e = 0; e < 8; ++e) o[e] = f2bf(T[kq + q * 8 + e][c]);
      *(u16x8*)(dst + (size_t)(drow0 + c0 + c) * dld + kr0 + kq + q * 8) = o;
    }
  } else if (blk < 2656) {        // Wc^T[n][i] = sum_j W1[(256+j)][n] * Wo[i][j]
    int wb = blk - 2144;
    int i = wb >> 1;
    int n = (wb & 1) * 256 + tid;
    float a[8] = {0.f, 0.f, 0.f, 0.f, 0.f, 0.f, 0.f, 0.f};
    for (int j = 0; j < 256; j += 8) {
#pragma unroll
      for (int e = 0; e < 8; ++e)
        a[e] = fmaf(Wo[i * 256 + j + e], W1[(size_t)(256 + j + e) * 512 + n], a[e]);
    }
    btF[(size_t)n * 512 + 256 + i] =
        f2bf(((a[0] + a[1]) + (a[2] + a[3])) + ((a[4] + a[5]) + (a[6] + a[7])));
  } else {                        // bc[n] = b1[n] + sum_j bo[j]*W1[(256+j)][n]
    int n = (blk - 2656) * 256 + tid;
    float p[8] = {0.f, 0.f, 0.f, 0.f, 0.f, 0.f, 0.f, 0.f};
    for (int j = 0; j < 256; j += 8) {
#pragma unroll
      for (int e = 0; e < 8; ++e)
        p[e] = fmaf(bo[j + e], W1[(size_t)(256 + j + e) * 512 + n], p[e]);
    }
    bc[n] = b1[n] + (((p[0] + p[1]) + (p[2] + p[3])) + ((p[4] + p[5]) + (p[6] + p[7])));
  }
}

// ---------------------------------------------------------------------------
// GEMM: C[16384 x Ncols] = A(bf16,[M][KD], split A1|A2 at K1) @ Bt^T
// Bt is [Ncols][KD] bf16. 128xBN tile, 4 waves, BK=32, double-buffered
// global_load_lds, XOR-swizzled LDS. BN=64 doubles blocks/CU for N=512
// outputs (latency/barrier-bound regime, not MFMA-bound).
// EPI 0: qk/vt scatter (+bias,*SS2 / +bias, packed-n stores)
// EPI 1: bf16 out (+bias)      EPI 3: f32 out (+bias +residual x)
// ---------------------------------------------------------------------------
template <int KD, int K1, int EPI, int BN>
__global__ __launch_bounds__(256, 2) void k_gemm(
    const u16* __restrict__ A1, const u16* __restrict__ A2,
    const u16* __restrict__ Bt,
    const float* __restrict__ bias, const float* __restrict__ bias2,
    const float* __restrict__ res0, const float* __restrict__ res1,
    u16* __restrict__ outb, u16* __restrict__ outb2,
    float* __restrict__ outf, int Ncols)
{
  constexpr int MR = (BN == 128) ? 4 : 2;       // row-tiles per wave
  __shared__ char lds[16384 + 2 * BN * 64];
  char* ldsA = lds;
  char* ldsB = lds + 16384;
  const int tid = threadIdx.x;
  const int lane = tid & 63;
  const int w = tid >> 6;
  const int wm = (BN == 128) ? (w >> 1) : w;
  const int wn = (BN == 128) ? (w & 1) : 0;
  const int g = lane >> 4, li = lane & 15;
  const int m0 = blockIdx.x * 128, n0 = blockIdx.y * BN;

  auto stage = [&](int buf, int t) {
    const int k0 = t * 32;
#pragma unroll
    for (int it = 0; it < 2; ++it) {
      int chunk = it * 256 + w * 64 + lane;
      int row = chunk >> 2, c = chunk & 3;
      int kc = k0 + ((c ^ ((row >> 1) & 3)) << 3);
      const u16* src = (kc < K1) ? (A1 + (size_t)(m0 + row) * K1 + kc)
                                 : (A2 + (size_t)(m0 + row) * (KD - K1) + (kc - K1));
      gload_lds16(src, ldsA + buf * 8192 + (it * 256 + w * 64) * 16);
    }
#pragma unroll
    for (int it = 0; it < BN / 64; ++it) {
      int chunk = it * 256 + w * 64 + lane;
      int row = chunk >> 2, c = chunk & 3;
      int kc = k0 + ((c ^ ((row >> 1) & 3)) << 3);
      gload_lds16(Bt + (size_t)(n0 + row) * KD + kc,
                  ldsB + buf * (BN * 64) + (it * 256 + w * 64) * 16);
    }
  };

  f32x4 acc[MR][4] = {};

  stage(0, 0);
  __syncthreads();
  const int NT = KD / 32;
  for (int t = 0; t < NT; ++t) {
    if (t + 1 < NT) stage((t + 1) & 1, t + 1);
    const char* bufA = ldsA + (t & 1) * 8192;
    const char* bufB = ldsB + (t & 1) * (BN * 64);
    s16x8 af[MR], bfr[4];
#pragma unroll
    for (int rt = 0; rt < MR; ++rt) {
      int row = wm * (MR * 16) + rt * 16 + li;
      af[rt] = *(const s16x8*)(bufA + row * 64 + ((g ^ ((row >> 1) & 3)) << 4));
    }
#pragma unroll
    for (int ct = 0; ct < 4; ++ct) {
      int col = wn * 64 + ct * 16 + li;
      bfr[ct] = *(const s16x8*)(bufB + col * 64 + ((g ^ ((col >> 1) & 3)) << 4));
    }
#pragma unroll
    for (int rt = 0; rt < MR; ++rt)
#pragma unroll
      for (int ct = 0; ct < 4; ++ct)
        acc[rt][ct] = mfma16(af[rt], bfr[ct], acc[rt][ct]);
    __syncthreads();
  }

#pragma unroll
  for (int rt = 0; rt < MR; ++rt) {
#pragma unroll
    for (int ct = 0; ct < 4; ++ct) {
      const int growb = m0 + wm * (MR * 16) + rt * 16 + g * 4;   // base row (r=0)
      const int gcol = n0 + wn * 64 + ct * 16 + li;
      if (EPI == 0) {
        const int dir = growb >> 13, bb = (growb >> 11) & 3, n = growb & 2047;
        if (gcol < 256) {
          const int h = gcol >> 6, dh = gcol & 63;
#pragma unroll
          for (int r = 0; r < 4; ++r) {
            float q = (acc[rt][ct][r] + bias[gcol]) * SS2;
            outb[((size_t)(dir * 16 + bb * 4 + h) * 2048 + (n + r)) * 64 + dh] = f2bf(q);
          }
        } else {
          const int c2 = gcol - 256, h = c2 >> 6, dh = c2 & 63;
          u16x4 pk;
#pragma unroll
          for (int r = 0; r < 4; ++r) pk[r] = f2bf(acc[rt][ct][r] + bias2[c2]);
          *(u16x4*)(outb2 + ((size_t)(dir * 16 + bb * 4 + h) * 64 + dh) * 2048 + n) = pk;
        }
      } else if (EPI == 1) {
#pragma unroll
        for (int r = 0; r < 4; ++r)
          outb[(size_t)(growb + r) * Ncols + gcol] = f2bf(acc[rt][ct][r] + bias[gcol]);
      } else {
#pragma unroll
        for (int r = 0; r < 4; ++r) {
          int grow = growb + r;
          float x = (grow < 8192) ? res0[(size_t)grow * 256 + gcol]
                                  : res1[(size_t)(grow - 8192) * 256 + gcol];
          outf[(size_t)grow * 256 + gcol] = acc[rt][ct][r] + bias[gcol] + x;
        }
      }
    }
  }
}

// ---------------------------------------------------------------------------
// attention v7: in-block split-KV (8 waves: half 0/1 x 4 q-waves of 32 rows).
// K staged via gload_lds; V read from L2 but ISSUED FIRST each jt (T14
// issue-early/use-late): V loads (oldest) -> stageK(jt+1) -> QK/exp/permlane
// phase hides the L2 latency -> PV waits vmcnt(4), K-staging stays in flight.
// P stays in registers (permlane32_swap, T12; cvt_pk packing).
// Row sums via ones-MFMA. Logits pre-scaled by sqrt(log2 e) -> raw v_exp_f32.
// ---------------------------------------------------------------------------
__global__ __launch_bounds__(512, 4) void k_attn(
    const u16* __restrict__ qk, const u16* __restrict__ vt, u16* __restrict__ m_all)
{
  __shared__ char Kl[2][2][8192];   // [half][buf]
  __shared__ float lsmall[128];     // half0 row-sums for combine
  const int tid = threadIdx.x, lane = tid & 63, w = tid >> 6;
  const int half = w >> 2, wq = w & 3;
  const int g = lane >> 4, li = lane & 15;
  const int sw = (blockIdx.x & 7) * 64 + (blockIdx.x >> 3);  // XCD chunking (512=8*64)
  const int qblk = sw & 15;
  const int p = sw >> 4;
  const int dir = p >> 4, bh = p & 15;
  const char* Qg = (const char*)qk + (size_t)p * 262144;
  const char* Kg = (const char*)qk + (size_t)((dir ^ 1) * 16 + bh) * 262144;
  const u16*  Vg = vt + (size_t)((dir ^ 1) * 16 + bh) * 131072;  // [dh=64][n=2048]
  const int q0 = qblk * 128 + wq * 32;
  const int perm = (li & 3) | ((li & 4) << 1) | ((li & 8) >> 1);  // swap bits 2,3

  // Q fragments in registers (reused across the whole j loop)
  s16x8 qf[2][2];
#pragma unroll
  for (int qt = 0; qt < 2; ++qt)
#pragma unroll
    for (int h = 0; h < 2; ++h)
      qf[qt][h] = *(const s16x8*)(Qg + (size_t)(q0 + qt * 16 + li) * 128 + h * 64 + g * 16);

  // all-ones B-fragment: V[k][*]=1 -> mfma gives row sums of P
  s16x8 onesf;
#pragma unroll
  for (int e = 0; e < 8; ++e) onesf[e] = (short)0x3F80;

  auto stageK = [&](int buf, int jt) {
    const int kb = half * 1024 + jt * 64;
#pragma unroll
    for (int it = 0; it < 2; ++it) {
      int chunk = it * 256 + wq * 64 + lane;
      int row = chunk >> 3, c = chunk & 7;
      int cc = (c ^ (row & 7)) << 4;
      gload_lds16(Kg + (size_t)(kb + row) * 128 + cc, &Kl[half][buf][chunk * 16]);
    }
  };

  f32x4 acco[2][4] = {};
  f32x4 accs[2] = {};

  stageK(0, 0);
  __syncthreads();
  for (int jt = 0; jt < 16; ++jt) {
    const int keyb = half * 1024 + jt * 64;   // key element base in V rows

    // 1. V fragment loads FIRST (oldest vmcnt entries; consumed by PV below)
    s16x8 vfr[4][2];
#pragma unroll
    for (int dt = 0; dt < 4; ++dt)
#pragma unroll
      for (int ks = 0; ks < 2; ++ks)
        vfr[dt][ks] = *(const s16x8*)(Vg + (size_t)(dt * 16 + li) * 2048 +
                                      keyb + ks * 32 + g * 8);

    // 2. K staging for next tile (younger; stays in flight through PV)
    if (jt + 1 < 16) stageK((jt + 1) & 1, jt + 1);
    const char* Kb = &Kl[half][jt & 1][0];

    // 3. S^T tiles: mfma(K,Q). K rows loaded at perm(li) so lane (g,li) holds
    // keys kt*16 + 8*(g&1) + 4*(g>>1) + r for q-row qt*16+li.
    u32 pw[4][2][2];  // [kt][qt][word]: packed bf16 pairs of exp2(S')
#pragma unroll
    for (int kt = 0; kt < 4; ++kt) {
      const int krow = kt * 16 + perm;
      s16x8 kf0 = *(const s16x8*)(Kb + krow * 128 + ((g ^ (krow & 7)) << 4));
      s16x8 kf1 = *(const s16x8*)(Kb + krow * 128 + (((4 + g) ^ (krow & 7)) << 4));
#pragma unroll
      for (int qt = 0; qt < 2; ++qt) {
        f32x4 s = {0.f, 0.f, 0.f, 0.f};
        s = mfma16(kf0, qf[qt][0], s);
        s = mfma16(kf1, qf[qt][1], s);
        pw[kt][qt][0] = cvtpk(fexp2(s[0]), fexp2(s[1]));
        pw[kt][qt][1] = cvtpk(fexp2(s[2]), fexp2(s[3]));
      }
    }

    // 4. Build PV A-frags in-register: two permlane32_swap per (ks,qt).
    s16x8 pf[2][2];  // [ks][qt]
#pragma unroll
    for (int ks = 0; ks < 2; ++ks)
#pragma unroll
      for (int qt = 0; qt < 2; ++qt) {
        u32 a0 = pw[ks * 2][qt][0], b0 = pw[ks * 2 + 1][qt][0];
        u32 a1 = pw[ks * 2][qt][1], b1 = pw[ks * 2 + 1][qt][1];
        asm("v_permlane32_swap_b32 %0, %1" : "+v"(a0), "+v"(b0));
        asm("v_permlane32_swap_b32 %0, %1" : "+v"(a1), "+v"(b1));
        u32 words[4] = {a0, a1, b0, b1};
        __builtin_memcpy(&pf[ks][qt], words, 16);
      }

    // 5. O += P V  (vfr arrived during phase 3); rowsums += P * ones
#pragma unroll
    for (int ks = 0; ks < 2; ++ks) {
      accs[0] = mfma16(pf[ks][0], onesf, accs[0]);
      accs[1] = mfma16(pf[ks][1], onesf, accs[1]);
#pragma unroll
      for (int dt = 0; dt < 4; ++dt) {
        acco[0][dt] = mfma16(pf[ks][0], vfr[dt][ks], acco[0][dt]);
        acco[1][dt] = mfma16(pf[ks][1], vfr[dt][ks], acco[1][dt]);
      }
    }
    __syncthreads();
  }

  // in-block half-combine through freed K-LDS (32KB O scratch) + lsmall.
  // accs[qt][r] at lane (g,li) = rowsum for q-row qt*16+g*4+r (all li equal).
  float* scr = (float*)&Kl[0][0][0];
  if (half == 0) {
#pragma unroll
    for (int qt = 0; qt < 2; ++qt)
#pragma unroll
      for (int dt = 0; dt < 4; ++dt)
        *(f32x4*)(scr + wq * 2048 + lane * 32 + (((qt * 4 + dt) * 4) ^ ((lane & 7) << 2))) =
            acco[qt][dt];
    if (li == 0) {
#pragma unroll
      for (int qt = 0; qt < 2; ++qt)
#pragma unroll
        for (int r = 0; r < 4; ++r)
          lsmall[wq * 32 + qt * 16 + g * 4 + r] = accs[qt][r];
    }
  }
  __syncthreads();
  if (half == 1) {
    const int bb = bh >> 2, h = bh & 3;
#pragma unroll
    for (int qt = 0; qt < 2; ++qt) {
      f32x4 lo = *(const f32x4*)(lsmall + wq * 32 + qt * 16 + g * 4);
      f32x4 inv;
#pragma unroll
      for (int r = 0; r < 4; ++r) inv[r] = 1.0f / (accs[qt][r] + lo[r]);
      const size_t rowb = (size_t)dir * 8192 + (size_t)bb * 2048 + q0 + qt * 16 + g * 4;
#pragma unroll
      for (int dt = 0; dt < 4; ++dt) {
        f32x4 o = *(const f32x4*)(scr + wq * 2048 + lane * 32 +
                                  (((qt * 4 + dt) * 4) ^ ((lane & 7) << 2)));
#pragma unroll
        for (int r = 0; r < 4; ++r)
          m_all[(rowb + r) * 256 + h * 64 + dt * 16 + li] =
              f2bf((acco[qt][dt][r] + o[r]) * inv[r]);
      }
    }
  }
}

// ---------------------------------------------------------------------------
// layernorm (over 512) + exact gelu; one wave per row
// ---------------------------------------------------------------------------
__global__ __launch_bounds__(256) void k_ln_gelu(
    const u16* __restrict__ h, const float* __restrict__ lg,
    const float* __restrict__ lb, u16* __restrict__ o)
{
  int lane = threadIdx.x & 63;
  size_t row = blockIdx.x * 4 + (threadIdx.x >> 6);
  s16x8 v = *(const s16x8*)(h + row * 512 + lane * 8);
  float f[8], s = 0.f, s2 = 0.f;
#pragma unroll
  for (int j = 0; j < 8; ++j) { f[j] = bf2f((u16)v[j]); s += f[j]; s2 += f[j] * f[j]; }
#pragma unroll
  for (int m = 1; m < 64; m <<= 1) { s += __shfl_xor(s, m); s2 += __shfl_xor(s2, m); }
  float mu = s * (1.0f / 512.0f);
  float var = s2 * (1.0f / 512.0f) - mu * mu;
  float rs = rsqrtf(var + 1e-5f);
  s16x8 ov;
#pragma unroll
  for (int j = 0; j < 8; ++j) {
    int c = lane * 8 + j;
    float y = (f[j] - mu) * rs * lg[c] + lb[c];
    float ge = 0.5f * y * (1.0f + erff(y * 0.70710678118654752f));
    ov[j] = (short)f2bf(ge);
  }
  *(s16x8*)(o + row * 512 + lane * 8) = ov;
}

// ---------------------------------------------------------------------------
extern "C" void kernel_launch(void* const* d_in, const int* in_sizes, int n_in,
                              void* d_out, int out_size, void* d_ws, size_t ws_size,
                              hipStream_t stream)
{
  const float* x0  = (const float*)d_in[0];
  const float* x1  = (const float*)d_in[1];
  const float* Wqk = (const float*)d_in[2];
  const float* bqk = (const float*)d_in[3];
  const float* Wv  = (const float*)d_in[4];
  const float* bv  = (const float*)d_in[5];
  const float* Wo  = (const float*)d_in[6];
  const float* bo  = (const float*)d_in[7];
  const float* W1  = (const float*)d_in[8];
  const float* b1  = (const float*)d_in[9];
  const float* lg  = (const float*)d_in[10];
  const float* lb  = (const float*)d_in[11];
  const float* W2  = (const float*)d_in[12];
  const float* b2  = (const float*)d_in[13];
  float* out = (float*)d_out;
  char* ws = (char*)d_ws;

  u16*   Xb    = (u16*)(ws + 0);          // 16384x256 bf16
  u16*   qk    = (u16*)(ws + 8388608);    // [2][4][4][2048][64] bf16 (scaled)
  u16*   vt    = (u16*)(ws + 16777216);   // [2][4][4][64][2048] bf16 (V^T)
  u16*   m_all = (u16*)(ws + 25165824);   // 16384x256 bf16 (normalized attn out)
  u16*   hpre  = (u16*)(ws + 33554432);   // 16384x512 bf16
  u16*   gact  = (u16*)(ws + 50331648);   // 16384x512 bf16
  u16*   btqkv = (u16*)(ws + 67108864);   // [512][256]
  u16*   btF   = (u16*)(ws + 67371008);   // [512][512]: [:, :256]=W1a^T, [:, 256:]=Wc^T
  u16*   bt2   = (u16*)(ws + 67895296);   // [256][512]
  float* bc    = (float*)(ws + 68419584); // [512] fused FFN1 bias

  k_prep<<<dim3(2658), dim3(256), 0, stream>>>(x0, x1, Wqk, Wv, Wo, W1, W2, bo, b1,
                                               btqkv, btF, bt2, bc, Xb);
  k_gemm<256, 256, 0, 64><<<dim3(128, 8), dim3(256), 0, stream>>>(
      Xb, nullptr, btqkv, bqk, bv, nullptr, nullptr, qk, vt, nullptr, 512);
  k_attn<<<dim3(512), dim3(512), 0, stream>>>(qk, vt, m_all);
  k_gemm<512, 256, 1, 64><<<dim3(128, 8), dim3(256), 0, stream>>>(
      Xb, m_all, btF, bc, nullptr, nullptr, nullptr, hpre, nullptr, nullptr, 512);
  k_ln_gelu<<<dim3(4096), dim3(256), 0, stream>>>(hpre, lg, lb, gact);
  k_gemm<512, 512, 3, 64><<<dim3(128, 4), dim3(256), 0, stream>>>(
      gact, nullptr, bt2, b2, nullptr, x0, x1, nullptr, nullptr, out, 256);
}

// Round 8
// 215.042 us; speedup vs baseline: 1.1697x; 1.1405x over previous
//
#include <hip/hip_runtime.h>
#include <hip/hip_bf16.h>
#include <math.h>

#define DEV static __device__ __forceinline__

typedef float f32x4 __attribute__((ext_vector_type(4)));
typedef short s16x8 __attribute__((ext_vector_type(8)));
typedef unsigned short u16;
typedef unsigned int u32;
typedef u16 u16x4 __attribute__((ext_vector_type(4)));
typedef u16 u16x8 __attribute__((ext_vector_type(8)));

#define SSCALE 0.35355339059327379f   // 64^-0.25
// SSCALE * sqrt(log2(e)): folds the exp->exp2 conversion into the symmetric
// qk scaling, so softmax uses raw v_exp_f32 with no per-element multiply.
#define SS2 0.42466089345200966f

DEV f32x4 mfma16(s16x8 a, s16x8 b, f32x4 c) {
  return __builtin_amdgcn_mfma_f32_16x16x32_bf16(a, b, c, 0, 0, 0);
}

DEV float bf2f(u16 x) { u32 u = ((u32)x) << 16; float f; __builtin_memcpy(&f, &u, 4); return f; }
DEV u16 f2bf(float x) { __hip_bfloat16 b = __float2bfloat16(x); u16 r; __builtin_memcpy(&r, &b, 2); return r; }

// packed f32x2 -> bf16x2 in one VALU op (T12 recipe; no builtin on gfx950)
DEV u32 cvtpk(float lo, float hi) {
  u32 r;
  asm("v_cvt_pk_bf16_f32 %0, %1, %2" : "=v"(r) : "v"(lo), "v"(hi));
  return r;
}

DEV float fexp2(float x) {
#if __has_builtin(__builtin_amdgcn_exp2f)
  return __builtin_amdgcn_exp2f(x);
#else
  return exp2f(x);
#endif
}

DEV void gload_lds16(const void* g, void* l) {
  __builtin_amdgcn_global_load_lds((const __attribute__((address_space(1))) u32*)g,
                                   (__attribute__((address_space(3))) u32*)l, 16, 0, 0);
}

// ---------------------------------------------------------------------------
// prep (multi-mode by block range):
//   [0,2048)    x0|x1 -> Xb bf16 (vectorized)
//   [2048,2144) 96 LDS-tiled 64x64 transposes: Wqk^T,Wv^T -> btqkv;
//               W1a^T -> btF[:, :256]; W2^T -> bt2
//   [2144,2656) Wc = Wo @ W1b (f32 accum, 8-way ILP) -> btF[:, 256:]
//   [2656,2658) bc = b1 + bo @ W1b (f32, 8-way ILP)
// ---------------------------------------------------------------------------
__global__ __launch_bounds__(256) void k_prep(
    const float* __restrict__ x0, const float* __restrict__ x1,
    const float* __restrict__ Wqk, const float* __restrict__ Wv,
    const float* __restrict__ Wo, const float* __restrict__ W1,
    const float* __restrict__ W2, const float* __restrict__ bo,
    const float* __restrict__ b1,
    u16* __restrict__ btqkv, u16* __restrict__ btF,
    u16* __restrict__ bt2, float* __restrict__ bc, u16* __restrict__ Xb)
{
  const int blk = blockIdx.x, tid = threadIdx.x;
  if (blk < 2048) {               // x convert: 2048 elems per block
    int idx = blk * 2048 + tid * 8;
    const float* src = (idx < 2097152) ? (x0 + idx) : (x1 + (idx - 2097152));
    f32x4 va = *(const f32x4*)src;
    f32x4 vb = *(const f32x4*)(src + 4);
    u16x8 o;
#pragma unroll
    for (int j = 0; j < 4; ++j) { o[j] = f2bf(va[j]); o[4 + j] = f2bf(vb[j]); }
    *(u16x8*)(Xb + idx) = o;
  } else if (blk < 2144) {        // transpose tiles
    __shared__ float T[64][65];
    int tb = blk - 2048;
    const float* src; u16* dst; int sld, dld, kr0, c0, drow0;
    if (tb < 16)      { src = Wqk; dst = btqkv; sld = 256; dld = 256; drow0 = 0;
                        kr0 = (tb >> 2) * 64; c0 = (tb & 3) * 64; }
    else if (tb < 32) { tb -= 16; src = Wv; dst = btqkv; sld = 256; dld = 256; drow0 = 256;
                        kr0 = (tb >> 2) * 64; c0 = (tb & 3) * 64; }
    else if (tb < 64) { tb -= 32; src = W1; dst = btF; sld = 512; dld = 512; drow0 = 0;
                        kr0 = (tb >> 3) * 64; c0 = (tb & 7) * 64; }
    else              { tb -= 64; src = W2; dst = bt2; sld = 256; dld = 512; drow0 = 0;
                        kr0 = (tb >> 2) * 64; c0 = (tb & 3) * 64; }
    int r = tid >> 2, cq = (tid & 3) * 16;
#pragma unroll
    for (int q = 0; q < 4; ++q) {
      f32x4 v = *(const f32x4*)(src + (size_t)(kr0 + r) * sld + c0 + cq + q * 4);
#pragma unroll
      for (int e = 0; e < 4; ++e) T[r][cq + q * 4 + e] = v[e];
    }
    __syncthreads();
    int c = tid >> 2, kq = (tid & 3) * 16;
#pragma unroll
    for (int q = 0; q < 2; ++q) {
      u16x8 o;
#pragma unroll
      for (int e = 0; e < 8; ++e) o[e] = f2bf(T[kq + q * 8 + e][c]);
      *(u16x8*)(dst + (size_t)(drow0 + c0 + c) * dld + kr0 + kq + q * 8) = o;
    }
  } else if (blk < 2656) {        // Wc^T[n][i] = sum_j W1[(256+j)][n] * Wo[i][j]
    int wb = blk - 2144;
    int i = wb >> 1;
    int n = (wb & 1) * 256 + tid;
    float a[8] = {0.f, 0.f, 0.f, 0.f, 0.f, 0.f, 0.f, 0.f};
    for (int j = 0; j < 256; j += 8) {
#pragma unroll
      for (int e = 0; e < 8; ++e)
        a[e] = fmaf(Wo[i * 256 + j + e], W1[(size_t)(256 + j + e) * 512 + n], a[e]);
    }
    btF[(size_t)n * 512 + 256 + i] =
        f2bf(((a[0] + a[1]) + (a[2] + a[3])) + ((a[4] + a[5]) + (a[6] + a[7])));
  } else {                        // bc[n] = b1[n] + sum_j bo[j]*W1[(256+j)][n]
    int n = (blk - 2656) * 256 + tid;
    float p[8] = {0.f, 0.f, 0.f, 0.f, 0.f, 0.f, 0.f, 0.f};
    for (int j = 0; j < 256; j += 8) {
#pragma unroll
      for (int e = 0; e < 8; ++e)
        p[e] = fmaf(bo[j + e], W1[(size_t)(256 + j + e) * 512 + n], p[e]);
    }
    bc[n] = b1[n] + (((p[0] + p[1]) + (p[2] + p[3])) + ((p[4] + p[5]) + (p[6] + p[7])));
  }
}

// ---------------------------------------------------------------------------
// GEMM: C[16384 x Ncols] = A(bf16,[M][KD], split A1|A2 at K1) @ Bt^T
// Bt is [Ncols][KD] bf16. 128xBN tile, 4 waves, BK=32, double-buffered
// global_load_lds, XOR-swizzled LDS.
// EPI 0: qk/vt scatter (+bias,*SS2 / +bias, packed-n stores)
// EPI 1: bf16 out (+bias)      EPI 3: f32 out (+bias +residual x)
// ---------------------------------------------------------------------------
template <int KD, int K1, int EPI, int BN>
__global__ __launch_bounds__(256, 2) void k_gemm(
    const u16* __restrict__ A1, const u16* __restrict__ A2,
    const u16* __restrict__ Bt,
    const float* __restrict__ bias, const float* __restrict__ bias2,
    const float* __restrict__ res0, const float* __restrict__ res1,
    u16* __restrict__ outb, u16* __restrict__ outb2,
    float* __restrict__ outf, int Ncols)
{
  constexpr int MR = (BN == 128) ? 4 : 2;       // row-tiles per wave
  __shared__ char lds[16384 + 2 * BN * 64];
  char* ldsA = lds;
  char* ldsB = lds + 16384;
  const int tid = threadIdx.x;
  const int lane = tid & 63;
  const int w = tid >> 6;
  const int wm = (BN == 128) ? (w >> 1) : w;
  const int wn = (BN == 128) ? (w & 1) : 0;
  const int g = lane >> 4, li = lane & 15;
  const int m0 = blockIdx.x * 128, n0 = blockIdx.y * BN;

  auto stage = [&](int buf, int t) {
    const int k0 = t * 32;
#pragma unroll
    for (int it = 0; it < 2; ++it) {
      int chunk = it * 256 + w * 64 + lane;
      int row = chunk >> 2, c = chunk & 3;
      int kc = k0 + ((c ^ ((row >> 1) & 3)) << 3);
      const u16* src = (kc < K1) ? (A1 + (size_t)(m0 + row) * K1 + kc)
                                 : (A2 + (size_t)(m0 + row) * (KD - K1) + (kc - K1));
      gload_lds16(src, ldsA + buf * 8192 + (it * 256 + w * 64) * 16);
    }
#pragma unroll
    for (int it = 0; it < BN / 64; ++it) {
      int chunk = it * 256 + w * 64 + lane;
      int row = chunk >> 2, c = chunk & 3;
      int kc = k0 + ((c ^ ((row >> 1) & 3)) << 3);
      gload_lds16(Bt + (size_t)(n0 + row) * KD + kc,
                  ldsB + buf * (BN * 64) + (it * 256 + w * 64) * 16);
    }
  };

  f32x4 acc[MR][4] = {};

  stage(0, 0);
  __syncthreads();
  const int NT = KD / 32;
  for (int t = 0; t < NT; ++t) {
    if (t + 1 < NT) stage((t + 1) & 1, t + 1);
    const char* bufA = ldsA + (t & 1) * 8192;
    const char* bufB = ldsB + (t & 1) * (BN * 64);
    s16x8 af[MR], bfr[4];
#pragma unroll
    for (int rt = 0; rt < MR; ++rt) {
      int row = wm * (MR * 16) + rt * 16 + li;
      af[rt] = *(const s16x8*)(bufA + row * 64 + ((g ^ ((row >> 1) & 3)) << 4));
    }
#pragma unroll
    for (int ct = 0; ct < 4; ++ct) {
      int col = wn * 64 + ct * 16 + li;
      bfr[ct] = *(const s16x8*)(bufB + col * 64 + ((g ^ ((col >> 1) & 3)) << 4));
    }
#pragma unroll
    for (int rt = 0; rt < MR; ++rt)
#pragma unroll
      for (int ct = 0; ct < 4; ++ct)
        acc[rt][ct] = mfma16(af[rt], bfr[ct], acc[rt][ct]);
    __syncthreads();
  }

#pragma unroll
  for (int rt = 0; rt < MR; ++rt) {
#pragma unroll
    for (int ct = 0; ct < 4; ++ct) {
      const int growb = m0 + wm * (MR * 16) + rt * 16 + g * 4;   // base row (r=0)
      const int gcol = n0 + wn * 64 + ct * 16 + li;
      if (EPI == 0) {
        const int dir = growb >> 13, bb = (growb >> 11) & 3, n = growb & 2047;
        if (gcol < 256) {
          const int h = gcol >> 6, dh = gcol & 63;
#pragma unroll
          for (int r = 0; r < 4; ++r) {
            float q = (acc[rt][ct][r] + bias[gcol]) * SS2;
            outb[((size_t)(dir * 16 + bb * 4 + h) * 2048 + (n + r)) * 64 + dh] = f2bf(q);
          }
        } else {
          const int c2 = gcol - 256, h = c2 >> 6, dh = c2 & 63;
          u16x4 pk;
#pragma unroll
          for (int r = 0; r < 4; ++r) pk[r] = f2bf(acc[rt][ct][r] + bias2[c2]);
          *(u16x4*)(outb2 + ((size_t)(dir * 16 + bb * 4 + h) * 64 + dh) * 2048 + n) = pk;
        }
      } else if (EPI == 1) {
#pragma unroll
        for (int r = 0; r < 4; ++r)
          outb[(size_t)(growb + r) * Ncols + gcol] = f2bf(acc[rt][ct][r] + bias[gcol]);
      } else {
#pragma unroll
        for (int r = 0; r < 4; ++r) {
          int grow = growb + r;
          float x = (grow < 8192) ? res0[(size_t)grow * 256 + gcol]
                                  : res1[(size_t)(grow - 8192) * 256 + gcol];
          outf[(size_t)grow * 256 + gcol] = acc[rt][ct][r] + bias[gcol] + x;
        }
      }
    }
  }
}

// ---------------------------------------------------------------------------
// attention v8 = v4 structure + VALU reductions.
// In-block split-KV: 8 waves (half 0/1 x 4 q-waves of 32 rows); K AND V
// double-buffered in LDS via gload_lds (v7 showed the compiler sinks direct
// L2 V-loads under register pressure -> LDS staging is the reliable path).
// VALU cuts proven in v6/v7 (VALUBusy 48->22%): exp2 prescale, cvt_pk
// packing, ones-MFMA row sums. P never touches LDS (permlane32_swap, T12).
// T5 setprio around the PV MFMA cluster.
// ---------------------------------------------------------------------------
__global__ __launch_bounds__(512, 4) void k_attn(
    const u16* __restrict__ qk, const u16* __restrict__ vt, u16* __restrict__ m_all)
{
  __shared__ char Kl[2][2][8192];   // [half][buf]
  __shared__ char Vl[2][2][8192];
  __shared__ float lsmall[128];     // half0 row-sums for combine
  const int tid = threadIdx.x, lane = tid & 63, w = tid >> 6;
  const int half = w >> 2, wq = w & 3;
  const int g = lane >> 4, li = lane & 15;
  const int sw = (blockIdx.x & 7) * 64 + (blockIdx.x >> 3);  // XCD chunking (512=8*64)
  const int qblk = sw & 15;
  const int p = sw >> 4;
  const int dir = p >> 4, bh = p & 15;
  const char* Qg = (const char*)qk + (size_t)p * 262144;
  const char* Kg = (const char*)qk + (size_t)((dir ^ 1) * 16 + bh) * 262144;
  const char* Vg = (const char*)vt + (size_t)((dir ^ 1) * 16 + bh) * 262144;
  const int q0 = qblk * 128 + wq * 32;
  const int perm = (li & 3) | ((li & 4) << 1) | ((li & 8) >> 1);  // swap bits 2,3

  // Q fragments in registers (reused across the whole j loop)
  s16x8 qf[2][2];
#pragma unroll
  for (int qt = 0; qt < 2; ++qt)
#pragma unroll
    for (int h = 0; h < 2; ++h)
      qf[qt][h] = *(const s16x8*)(Qg + (size_t)(q0 + qt * 16 + li) * 128 + h * 64 + g * 16);

  // all-ones B-fragment: mfma(P, ones) -> row sums of P land exactly at the
  // lanes that need them (C col = li, all cols equal)
  s16x8 onesf;
#pragma unroll
  for (int e = 0; e < 8; ++e) onesf[e] = (short)0x3F80;

  auto stageKV = [&](int buf, int jt) {
    const int kb = half * 1024 + jt * 64;    // key base for this half
#pragma unroll
    for (int it = 0; it < 2; ++it) {
      int chunk = it * 256 + wq * 64 + lane;
      int row = chunk >> 3, c = chunk & 7;
      int cc = (c ^ (row & 7)) << 4;
      gload_lds16(Kg + (size_t)(kb + row) * 128 + cc, &Kl[half][buf][chunk * 16]);
    }
#pragma unroll
    for (int it = 0; it < 2; ++it) {
      int chunk = it * 256 + wq * 64 + lane;
      int row = chunk >> 3, c = chunk & 7;
      int cc = (c ^ (row & 7)) << 4;
      gload_lds16(Vg + (size_t)row * 4096 + kb * 2 + cc, &Vl[half][buf][chunk * 16]);
    }
  };

  f32x4 acco[2][4] = {};
  f32x4 accs[2] = {};

  stageKV(0, 0);
  __syncthreads();
  for (int jt = 0; jt < 16; ++jt) {
    if (jt + 1 < 16) stageKV((jt + 1) & 1, jt + 1);
    const char* Kb = &Kl[half][jt & 1][0];
    const char* Vb = &Vl[half][jt & 1][0];

    // S^T tiles: mfma(K,Q). K rows loaded at perm(li) so lane (g,li) holds
    // keys kt*16 + 8*(g&1) + 4*(g>>1) + r for q-row qt*16+li.
    u32 pw[4][2][2];  // [kt][qt][word]: packed bf16 pairs of exp2(S')
#pragma unroll
    for (int kt = 0; kt < 4; ++kt) {
      const int krow = kt * 16 + perm;
      s16x8 kf0 = *(const s16x8*)(Kb + krow * 128 + ((g ^ (krow & 7)) << 4));
      s16x8 kf1 = *(const s16x8*)(Kb + krow * 128 + (((4 + g) ^ (krow & 7)) << 4));
#pragma unroll
      for (int qt = 0; qt < 2; ++qt) {
        f32x4 s = {0.f, 0.f, 0.f, 0.f};
        s = mfma16(kf0, qf[qt][0], s);
        s = mfma16(kf1, qf[qt][1], s);
        pw[kt][qt][0] = cvtpk(fexp2(s[0]), fexp2(s[1]));
        pw[kt][qt][1] = cvtpk(fexp2(s[2]), fexp2(s[3]));
      }
    }

    // Build PV A-frags in-register: two permlane32_swap per (ks,qt).
    s16x8 pf[2][2];  // [ks][qt]
#pragma unroll
    for (int ks = 0; ks < 2; ++ks)
#pragma unroll
      for (int qt = 0; qt < 2; ++qt) {
        u32 a0 = pw[ks * 2][qt][0], b0 = pw[ks * 2 + 1][qt][0];
        u32 a1 = pw[ks * 2][qt][1], b1 = pw[ks * 2 + 1][qt][1];
        asm("v_permlane32_swap_b32 %0, %1" : "+v"(a0), "+v"(b0));
        asm("v_permlane32_swap_b32 %0, %1" : "+v"(a1), "+v"(b1));
        u32 words[4] = {a0, a1, b0, b1};
        __builtin_memcpy(&pf[ks][qt], words, 16);
      }

    // O += P V ; rowsums += P * ones   (T5: boost prio through MFMA cluster)
    __builtin_amdgcn_s_setprio(1);
#pragma unroll
    for (int ks = 0; ks < 2; ++ks) {
      accs[0] = mfma16(pf[ks][0], onesf, accs[0]);
      accs[1] = mfma16(pf[ks][1], onesf, accs[1]);
#pragma unroll
      for (int dt = 0; dt < 4; ++dt) {
        const int vrow = dt * 16 + li;
        s16x8 vfr = *(const s16x8*)(Vb + vrow * 128 + (((ks * 4 + g) ^ (vrow & 7)) << 4));
        acco[0][dt] = mfma16(pf[ks][0], vfr, acco[0][dt]);
        acco[1][dt] = mfma16(pf[ks][1], vfr, acco[1][dt]);
      }
    }
    __builtin_amdgcn_s_setprio(0);
    __syncthreads();
  }

  // in-block half-combine through freed K-LDS (32KB O scratch) + lsmall.
  // accs[qt][r] at lane (g,li) = rowsum for q-row qt*16+g*4+r (all li equal).
  float* scr = (float*)&Kl[0][0][0];
  if (half == 0) {
#pragma unroll
    for (int qt = 0; qt < 2; ++qt)
#pragma unroll
      for (int dt = 0; dt < 4; ++dt)
        *(f32x4*)(scr + wq * 2048 + lane * 32 + (((qt * 4 + dt) * 4) ^ ((lane & 7) << 2))) =
            acco[qt][dt];
    if (li == 0) {
#pragma unroll
      for (int qt = 0; qt < 2; ++qt)
#pragma unroll
        for (int r = 0; r < 4; ++r)
          lsmall[wq * 32 + qt * 16 + g * 4 + r] = accs[qt][r];
    }
  }
  __syncthreads();
  if (half == 1) {
    const int bb = bh >> 2, h = bh & 3;
#pragma unroll
    for (int qt = 0; qt < 2; ++qt) {
      f32x4 lo = *(const f32x4*)(lsmall + wq * 32 + qt * 16 + g * 4);
      f32x4 inv;
#pragma unroll
      for (int r = 0; r < 4; ++r) inv[r] = 1.0f / (accs[qt][r] + lo[r]);
      const size_t rowb = (size_t)dir * 8192 + (size_t)bb * 2048 + q0 + qt * 16 + g * 4;
#pragma unroll
      for (int dt = 0; dt < 4; ++dt) {
        f32x4 o = *(const f32x4*)(scr + wq * 2048 + lane * 32 +
                                  (((qt * 4 + dt) * 4) ^ ((lane & 7) << 2)));
#pragma unroll
        for (int r = 0; r < 4; ++r)
          m_all[(rowb + r) * 256 + h * 64 + dt * 16 + li] =
              f2bf((acco[qt][dt][r] + o[r]) * inv[r]);
      }
    }
  }
}

// ---------------------------------------------------------------------------
// layernorm (over 512) + exact gelu; one wave per row
// ---------------------------------------------------------------------------
__global__ __launch_bounds__(256) void k_ln_gelu(
    const u16* __restrict__ h, const float* __restrict__ lg,
    const float* __restrict__ lb, u16* __restrict__ o)
{
  int lane = threadIdx.x & 63;
  size_t row = blockIdx.x * 4 + (threadIdx.x >> 6);
  s16x8 v = *(const s16x8*)(h + row * 512 + lane * 8);
  float f[8], s = 0.f, s2 = 0.f;
#pragma unroll
  for (int j = 0; j < 8; ++j) { f[j] = bf2f((u16)v[j]); s += f[j]; s2 += f[j] * f[j]; }
#pragma unroll
  for (int m = 1; m < 64; m <<= 1) { s += __shfl_xor(s, m); s2 += __shfl_xor(s2, m); }
  float mu = s * (1.0f / 512.0f);
  float var = s2 * (1.0f / 512.0f) - mu * mu;
  float rs = rsqrtf(var + 1e-5f);
  s16x8 ov;
#pragma unroll
  for (int j = 0; j < 8; ++j) {
    int c = lane * 8 + j;
    float y = (f[j] - mu) * rs * lg[c] + lb[c];
    float ge = 0.5f * y * (1.0f + erff(y * 0.70710678118654752f));
    ov[j] = (short)f2bf(ge);
  }
  *(s16x8*)(o + row * 512 + lane * 8) = ov;
}

// ---------------------------------------------------------------------------
extern "C" void kernel_launch(void* const* d_in, const int* in_sizes, int n_in,
                              void* d_out, int out_size, void* d_ws, size_t ws_size,
                              hipStream_t stream)
{
  const float* x0  = (const float*)d_in[0];
  const float* x1  = (const float*)d_in[1];
  const float* Wqk = (const float*)d_in[2];
  const float* bqk = (const float*)d_in[3];
  const float* Wv  = (const float*)d_in[4];
  const float* bv  = (const float*)d_in[5];
  const float* Wo  = (const float*)d_in[6];
  const float* bo  = (const float*)d_in[7];
  const float* W1  = (const float*)d_in[8];
  const float* b1  = (const float*)d_in[9];
  const float* lg  = (const float*)d_in[10];
  const float* lb  = (const float*)d_in[11];
  const float* W2  = (const float*)d_in[12];
  const float* b2  = (const float*)d_in[13];
  float* out = (float*)d_out;
  char* ws = (char*)d_ws;

  u16*   Xb    = (u16*)(ws + 0);          // 16384x256 bf16
  u16*   qk    = (u16*)(ws + 8388608);    // [2][4][4][2048][64] bf16 (scaled)
  u16*   vt    = (u16*)(ws + 16777216);   // [2][4][4][64][2048] bf16 (V^T)
  u16*   m_all = (u16*)(ws + 25165824);   // 16384x256 bf16 (normalized attn out)
  u16*   hpre  = (u16*)(ws + 33554432);   // 16384x512 bf16
  u16*   gact  = (u16*)(ws + 50331648);   // 16384x512 bf16
  u16*   btqkv = (u16*)(ws + 67108864);   // [512][256]
  u16*   btF   = (u16*)(ws + 67371008);   // [512][512]: [:, :256]=W1a^T, [:, 256:]=Wc^T
  u16*   bt2   = (u16*)(ws + 67895296);   // [256][512]
  float* bc    = (float*)(ws + 68419584); // [512] fused FFN1 bias

  k_prep<<<dim3(2658), dim3(256), 0, stream>>>(x0, x1, Wqk, Wv, Wo, W1, W2, bo, b1,
                                               btqkv, btF, bt2, bc, Xb);
  k_gemm<256, 256, 0, 128><<<dim3(128, 4), dim3(256), 0, stream>>>(
      Xb, nullptr, btqkv, bqk, bv, nullptr, nullptr, qk, vt, nullptr, 512);
  k_attn<<<dim3(512), dim3(512), 0, stream>>>(qk, vt, m_all);
  k_gemm<512, 256, 1, 128><<<dim3(128, 4), dim3(256), 0, stream>>>(
      Xb, m_all, btF, bc, nullptr, nullptr, nullptr, hpre, nullptr, nullptr, 512);
  k_ln_gelu<<<dim3(4096), dim3(256), 0, stream>>>(hpre, lg, lb, gact);
  k_gemm<512, 512, 3, 64><<<dim3(128, 4), dim3(256), 0, stream>>>(
      gact, nullptr, bt2, b2, nullptr, x0, x1, nullptr, nullptr, out, 256);
}